// Round 10
// baseline (1797.869 us; speedup 1.0000x reference)
//
#include <hip/hip_runtime.h>

typedef unsigned short u16;
typedef unsigned int u32;

#define NN 10000      // nodes
#define NE 320000     // edges
#define ET 330000     // edges + self loops
#define NB 262144     // batch
#define SHST 1792     // stats shard stride (floats)

typedef __attribute__((ext_vector_type(8))) short bf16x8;
typedef __attribute__((ext_vector_type(4))) float f32x4;

__device__ __forceinline__ u16 f2b(float f) {
  u32 u = __float_as_uint(f);
  u += 0x7fffu + ((u >> 16) & 1u);
  return (u16)(u >> 16);
}
__device__ __forceinline__ float b2f(u16 h) {
  return __uint_as_float(((u32)h) << 16);
}
__device__ __forceinline__ float lrelu(float v, float s) { return v > 0.f ? v : v * s; }

__device__ __forceinline__ void g2lds16(const void* g, void* l) {
  __builtin_amdgcn_global_load_lds((const __attribute__((address_space(1))) void*)g,
                                   (__attribute__((address_space(3))) void*)l, 16, 0, 0);
}

template <int N> __device__ __forceinline__ void waitv() {
  if constexpr (N == 0) asm volatile("s_waitcnt vmcnt(0)" ::: "memory");
  else if constexpr (N == 1) asm volatile("s_waitcnt vmcnt(1)" ::: "memory");
  else if constexpr (N == 2) asm volatile("s_waitcnt vmcnt(2)" ::: "memory");
  else if constexpr (N == 3) asm volatile("s_waitcnt vmcnt(3)" ::: "memory");
  else if constexpr (N == 4) asm volatile("s_waitcnt vmcnt(4)" ::: "memory");
  else if constexpr (N == 5) asm volatile("s_waitcnt vmcnt(5)" ::: "memory");
  else asm volatile("s_waitcnt vmcnt(6)" ::: "memory");
}
__device__ __forceinline__ void waitl0() { asm volatile("s_waitcnt lgkmcnt(0)" ::: "memory"); }
__device__ __forceinline__ void fence() { asm volatile("" ::: "memory"); }

// h-tile swizzled index: rows stride 256 u16; XOR spreads 8 rows across 8x16B slots
__device__ __forceinline__ int HIDX(int row, int col) {
  return (row * 256 + col) ^ ((row & 7) << 3);
}

// ---------------- merged prep ----------------
__global__ __launch_bounds__(256) void k_prep(const float* __restrict__ eW2, const float* __restrict__ eW3,
                                              const float* __restrict__ eW4, const float* __restrict__ eWo,
                                              const float* __restrict__ fW1, const float* __restrict__ fW2,
                                              const float* __restrict__ fW3, const float* __restrict__ fW4,
                                              const float* __restrict__ eW1,
                                              u16* eW2b, u16* eW3b, u16* eW4b,
                                              u16* fW2b, u16* fW3b, u16* fW4b,
                                              float* W1T, float* w512, u16* wTail) {
  const int blk = blockIdx.x, tid = threadIdx.x;
  if (blk < 256) {
    int t = blk * 256 + tid; eW2b[t] = f2b(eW2[t]);
  } else if (blk < 512) {
    int t = (blk - 256) * 256 + tid; eW3b[t] = f2b(eW3[t]);
  } else if (blk < 640) {
    int t = (blk - 512) * 256 + tid; eW4b[t] = f2b(eW4[t]);
  } else if (blk < 896) {
    int t = (blk - 640) * 256 + tid; fW2b[t] = f2b(fW2[t]);
  } else if (blk < 1152) {
    int t = (blk - 896) * 256 + tid; fW3b[t] = f2b(fW3[t]);
  } else if (blk < 1280) {
    int t = (blk - 1152) * 256 + tid; fW4b[t] = f2b(fW4[t]);
  } else if (blk < 1536) {
    int m = blk - 1280;
    for (int k = tid; k < 512; k += 256) W1T[(size_t)k * 256 + m] = eW1[(size_t)m * 513 + k];
  } else if (blk == 1536) {
    w512[tid] = eW1[(size_t)tid * 513 + 512];
  } else if (blk < 1577) {
    int t = (blk - 1537) * 256 + tid;   // 64 rows x 160
    int r = t / 160, k = t - r * 160;
    wTail[(size_t)r * 160 + k] = (k < 128) ? f2b(eWo[(size_t)r * 128 + k]) : (u16)0;
  } else {
    int m = blk - 1577;   // row 64+m
    int k = tid;
    if (k < 160) {
      float v = 0.f;
      if (k < 128) {
        const float* fr = fW1 + (size_t)m * 69;
        for (int j = 0; j < 64; ++j) v += fr[j] * eWo[(size_t)j * 128 + k];
      } else if (k < 133) {
        v = fW1[(size_t)m * 69 + 64 + (k - 128)];
      }
      wTail[(size_t)(64 + m) * 160 + k] = f2b(v);
    }
  }
}

// distb + compact S row (8 bf16 per batch element)
__global__ __launch_bounds__(256) void k_sprep(const int* __restrict__ od, const float* __restrict__ dm,
                                               const float* __restrict__ nv,
                                               float* __restrict__ distb, u16* __restrict__ sbuf) {
  int b = blockIdx.x * 256 + threadIdx.x;
  int o = od[b * 2], d = od[b * 2 + 1];
  float dist = dm[(size_t)o * NN + d];
  distb[b] = dist;
  bf16x8 r;
  r[0] = (short)f2b(nv[o * 2]);
  r[1] = (short)f2b(nv[d * 2]);
  r[2] = (short)f2b(nv[o * 2 + 1]);
  r[3] = (short)f2b(nv[d * 2 + 1]);
  r[4] = (short)f2b(dist);
  r[5] = 0; r[6] = 0; r[7] = 0;
  *(bf16x8*)(sbuf + (size_t)b * 8) = r;
}

// ---------------- dual-graph CSR build ----------------
__global__ __launch_bounds__(256) void k_count2(const int* __restrict__ ei0, const int* __restrict__ ei1,
                                                int* __restrict__ cnt) {
  int t = blockIdx.x * 256 + threadIdx.x;
  if (t >= 2 * ET) return;
  int g = t >= ET; int e = t - g * ET;
  const int* ei = g ? ei1 : ei0;
  int d = (e < NE) ? ei[NE + e] : (e - NE);
  atomicAdd(&cnt[g * NN + d], 1);
}

__global__ __launch_bounds__(1024) void k_scan2(const int* __restrict__ cnt, int* __restrict__ cs) {
  const int g = blockIdx.x;
  cnt += g * NN; cs += g * (NN + 1);
  __shared__ int part[1024];
  int tid = threadIdx.x;
  int base = tid * 10;
  int local[10];
  int s = 0;
#pragma unroll
  for (int i = 0; i < 10; ++i) {
    int idx = base + i;
    int v = (idx < NN) ? cnt[idx] : 0;
    local[i] = s; s += v;
  }
  part[tid] = s;
  __syncthreads();
  for (int off = 1; off < 1024; off <<= 1) {
    int v = (tid >= off) ? part[tid - off] : 0;
    __syncthreads();
    part[tid] += v;
    __syncthreads();
  }
  int pre = (tid > 0) ? part[tid - 1] : 0;
#pragma unroll
  for (int i = 0; i < 10; ++i) {
    int idx = base + i;
    if (idx < NN) cs[idx] = pre + local[i];
  }
  if (tid == 1023) cs[NN] = part[1023];
}

__global__ __launch_bounds__(256) void k_fill2(const int* __restrict__ ei0, const int* __restrict__ ei1,
                                               const int* __restrict__ cs, int* __restrict__ wr,
                                               int2* __restrict__ csr) {
  int t = blockIdx.x * 256 + threadIdx.x;
  if (t >= 2 * ET) return;
  int g = t >= ET; int e = t - g * ET;
  const int* ei = g ? ei1 : ei0;
  int s, d;
  if (e < NE) { s = ei[e]; d = ei[NE + e]; } else { s = e - NE; d = s; }
  int pos = atomicAdd(&wr[g * NN + d], 1);
  csr[(size_t)g * ET + cs[g * (NN + 1) + d] + pos] = make_int2(e, s);
}

__global__ __launch_bounds__(256) void k_asum2(const int2* __restrict__ csr, const int* __restrict__ cs,
                                               const float* __restrict__ ea0, const float* __restrict__ ea1,
                                               float* __restrict__ asum) {
  int wid = (blockIdx.x * 256 + threadIdx.x) >> 6;
  int lane = threadIdx.x & 63;
  int g = wid >= NN; int n = wid - g * NN;
  const float* ea = g ? ea1 : ea0;
  const int* csg = cs + g * (NN + 1);
  const int2* csrg = csr + (size_t)g * ET;
  int beg = csg[n], end = csg[n + 1];
  int j = lane & 7, slot = lane >> 3;
  float acc = 0.f;
  for (int i = beg + slot; i < end; i += 8) {
    int e = csrg[i].x;
    if (e < NE) acc += ea[(size_t)e * 8 + j];
  }
  acc += __shfl_xor(acc, 8);
  acc += __shfl_xor(acc, 16);
  acc += __shfl_xor(acc, 32);
  if (lane < 8) {
    float dr = (float)(end - beg - 1);
    asum[(size_t)wid * 8 + lane] = acc / fmaxf(dr, 1.f);
  }
}

// ---------------- dual-graph GAT ----------------
__global__ __launch_bounds__(256) void k_xlr2(const float* __restrict__ x0, const float* __restrict__ x1,
                                              const float* __restrict__ Wl0, const float* __restrict__ bl0,
                                              const float* __restrict__ Wr0, const float* __restrict__ br0,
                                              const float* __restrict__ Wl1, const float* __restrict__ bl1,
                                              const float* __restrict__ Wr1, const float* __restrict__ br1,
                                              float* __restrict__ xl, float* __restrict__ xr) {
  const int g = blockIdx.x >= NN / 2;
  const int lb = blockIdx.x - g * (NN / 2);
  const float* x = g ? x1 : x0;
  const float* Wl = g ? Wl1 : Wl0;
  const float* bl = g ? bl1 : bl0;
  const float* Wr = g ? Wr1 : Wr0;
  const float* br = g ? br1 : br0;
  xl += (size_t)g * NN * 128; xr += (size_t)g * NN * 128;
  __shared__ float sx[128];
  int nb = lb * 2;
  for (int i = threadIdx.x; i < 128; i += 256) sx[i] = x[(size_t)nb * 64 + i];
  __syncthreads();
  int half = threadIdx.x >> 7;
  int node = nb + half;
  int m = threadIdx.x & 127;
  const float* xv = sx + (half << 6);
  float al = bl[m], ar = br[m];
  const float* wl = Wl + (size_t)m * 64;
  const float* wr = Wr + (size_t)m * 64;
#pragma unroll 8
  for (int k = 0; k < 64; ++k) { float xk = xv[k]; al += xk * wl[k]; ar += xk * wr[k]; }
  xl[(size_t)node * 128 + m] = al;
  xr[(size_t)node * 128 + m] = ar;
}

__global__ __launch_bounds__(256) void k_scr2(const float* __restrict__ xl, const float* __restrict__ xr,
                                              const int* __restrict__ ei0, const int* __restrict__ ei1,
                                              const float* __restrict__ ea0, const float* __restrict__ ea1,
                                              const float* __restrict__ asum,
                                              const float* __restrict__ We0, const float* __restrict__ We1,
                                              const float* __restrict__ att0, const float* __restrict__ att1,
                                              float* __restrict__ scr) {
  const int g = blockIdx.x >= 2048;
  const int lb = blockIdx.x - g * 2048;
  const int* ei = g ? ei1 : ei0;
  const float* ea = g ? ea1 : ea0;
  const float* We = g ? We1 : We0;
  const float* att = g ? att1 : att0;
  const float* mattr = asum + (size_t)g * NN * 8;
  const float* xlg = xl + (size_t)g * NN * 128;
  const float* xrg = xr + (size_t)g * NN * 128;
  float* scrg = scr + (size_t)g * ET * 4;

  const int lane = threadIdx.x & 63;
  const int sub = lane & 31;
  const int half = lane >> 5;
  float4 w0[4], w1[4];
#pragma unroll
  for (int c = 0; c < 4; ++c) {
    const float* wp = We + (size_t)(sub * 4 + c) * 8;
    w0[c] = *(const float4*)wp;
    w1[c] = *(const float4*)(wp + 4);
  }
  const float4 attv = *(const float4*)(att + sub * 4);
  const int gw = (lb * 256 + threadIdx.x) >> 6;
  const int nw = 2048 * 4;
  for (int p = gw; p < ET / 2; p += nw) {
    int e = p * 2 + half;
    int s, d; const float* ap;
    if (e < NE) { s = ei[e]; d = ei[NE + e]; ap = ea + (size_t)e * 8; }
    else { s = e - NE; d = s; ap = mattr + (size_t)(e - NE) * 8; }
    float4 a0 = *(const float4*)ap;
    float4 a1 = *(const float4*)(ap + 4);
    float4 xlv = *(const float4*)(xlg + (size_t)s * 128 + sub * 4);
    float4 xrv = *(const float4*)(xrg + (size_t)d * 128 + sub * 4);
    const float* xle = (const float*)&xlv;
    const float* xre = (const float*)&xrv;
    const float* ate = (const float*)&attv;
    float psum = 0.f;
#pragma unroll
    for (int c = 0; c < 4; ++c) {
      float em = a0.x * w0[c].x + a0.y * w0[c].y + a0.z * w0[c].z + a0.w * w0[c].w
               + a1.x * w1[c].x + a1.y * w1[c].y + a1.z * w1[c].z + a1.w * w1[c].w;
      float v = xle[c] + xre[c] + em;
      v = v > 0.f ? v : 0.2f * v;
      psum += v * ate[c];
    }
    psum += __shfl_xor(psum, 1);
    psum += __shfl_xor(psum, 2);
    psum += __shfl_xor(psum, 4);
    if ((sub & 7) == 0) scrg[(size_t)e * 4 + (sub >> 3)] = psum;
  }
}

__global__ __launch_bounds__(256) void k_nodered2(const float* __restrict__ scr, const int2* __restrict__ csr,
                                                  const int* __restrict__ cs, const float* __restrict__ xl,
                                                  const float* __restrict__ bias0, const float* __restrict__ bias1,
                                                  float* __restrict__ m_out, float* __restrict__ den_out,
                                                  float* __restrict__ n1, float* __restrict__ n2) {
  int dd = (blockIdx.x * 256 + threadIdx.x) >> 6;
  int lane = threadIdx.x & 63;
  int g = dd >= NN; int d = dd - g * NN;
  const float* scrg = scr + (size_t)g * ET * 4;
  const int2* csrg = csr + (size_t)g * ET;
  const int* csg = cs + g * (NN + 1);
  const float* xlg = xl + (size_t)g * NN * 128;
  const float* bias = g ? bias1 : bias0;
  float* mo = m_out + (size_t)g * NN * 4;
  float* dn = den_out + (size_t)g * NN * 4;
  float* nout = g ? n2 : n1;

  int h0 = lane >> 5;
  int beg = csg[d], end = csg[d + 1];
  float mx0 = -3.4e38f, mx1 = -3.4e38f;
  for (int i = beg; i < end; ++i) {
    int e = csrg[i].x;
    mx0 = fmaxf(mx0, scrg[(size_t)e * 4 + h0]);
    mx1 = fmaxf(mx1, scrg[(size_t)e * 4 + h0 + 2]);
  }
  float acc0 = 0.f, acc1 = 0.f, dn0 = 0.f, dn1 = 0.f;
  for (int i = beg; i < end; ++i) {
    int2 es = csrg[i];
    float ex0 = __expf(scrg[(size_t)es.x * 4 + h0] - mx0);
    float ex1 = __expf(scrg[(size_t)es.x * 4 + h0 + 2] - mx1);
    dn0 += ex0; dn1 += ex1;
    const float* xp = xlg + (size_t)es.y * 128;
    acc0 += ex0 * xp[lane];
    acc1 += ex1 * xp[64 + lane];
  }
  if (lane == 0 || lane == 32) {
    mo[d * 4 + h0] = mx0;     mo[d * 4 + h0 + 2] = mx1;
    dn[d * 4 + h0] = dn0;     dn[d * 4 + h0 + 2] = dn1;
  }
  nout[(size_t)d * 128 + lane] = fmaxf(acc0 / dn0 + bias[lane], 0.f);
  nout[(size_t)d * 128 + 64 + lane] = fmaxf(acc1 / dn1 + bias[64 + lane], 0.f);
}

__global__ __launch_bounds__(256) void k_alpha2(const float* __restrict__ scr,
                                                const int* __restrict__ ei0, const int* __restrict__ ei1,
                                                const float* __restrict__ m, const float* __restrict__ den,
                                                float* __restrict__ a1, float* __restrict__ a2) {
  int t = blockIdx.x * 256 + threadIdx.x;
  if (t >= 2 * ET * 4) return;
  int g = t >= ET * 4; int tt = t - g * ET * 4;
  int e = tt >> 2, h = tt & 3;
  const int* ei = g ? ei1 : ei0;
  int d = (e < NE) ? ei[NE + e] : (e - NE);
  const float* mg = m + (size_t)g * NN * 4;
  const float* dg = den + (size_t)g * NN * 4;
  float* aout = g ? a2 : a1;
  aout[tt] = __expf(scr[(size_t)g * ET * 4 + tt] - mg[d * 4 + h]) / dg[d * 4 + h];
}

// ---------------- evo L1 factorization (bf16 tables) ----------------
__global__ __launch_bounds__(256) void k_qtab(const float* __restrict__ n1, const float* __restrict__ n2,
                                              const float* __restrict__ W1T,
                                              u16* __restrict__ Qo, u16* __restrict__ Qd) {
  __shared__ float s1[2048], s2[2048];
  int nb = blockIdx.x * 16;
  for (int i = threadIdx.x; i < 2048; i += 256) {
    s1[i] = n1[(size_t)nb * 128 + i];
    s2[i] = n2[(size_t)nb * 128 + i];
  }
  __syncthreads();
  int m = threadIdx.x;
  float qo[16], qd[16];
#pragma unroll
  for (int i = 0; i < 16; ++i) { qo[i] = 0.f; qd[i] = 0.f; }
#pragma unroll 2
  for (int k = 0; k < 128; ++k) {
    float w0 = W1T[(size_t)k * 256 + m];
    float w1 = W1T[(size_t)(128 + k) * 256 + m];
    float w2 = W1T[(size_t)(256 + k) * 256 + m];
    float w3 = W1T[(size_t)(384 + k) * 256 + m];
#pragma unroll
    for (int i = 0; i < 16; ++i) {
      float a = s1[i * 128 + k], b = s2[i * 128 + k];
      qo[i] += a * w0 + b * w2;
      qd[i] += a * w1 + b * w3;
    }
  }
#pragma unroll
  for (int i = 0; i < 16; ++i) {
    Qo[(size_t)(nb + i) * 256 + m] = f2b(qo[i]);
    Qd[(size_t)(nb + i) * 256 + m] = f2b(qd[i]);
  }
}

// ---------------- fused stage: acc += hT(A) @ W^T, B single-buf LDS + reg prefetch ----------------
template <int NF2, int KK, int M2>
__device__ __forceinline__ void fusedStage(const u16* __restrict__ Wsrc, u16* hT, u16* B2,
                                           int tid, f32x4 acc[8][NF2]) {
  const int lane = tid & 63, w = tid >> 6, wr = w >> 2, wc = w & 3;
  const int lr = lane & 15, lk = (lane >> 4) << 3;
  constexpr int KT = KK >> 5;
  constexpr int NCH = (M2 * 4 + 511) / 512;
  // preload B(0)
  {
    bf16x8 rB[NCH];
    int c = 0;
    for (int i = tid; i < M2 * 4; i += 512) {
      int row = i >> 2, part = i & 3;
      rB[c++] = *(const bf16x8*)(Wsrc + (size_t)row * KK + part * 8);
    }
    waitv<0>();
    c = 0;
    for (int i = tid; i < M2 * 4; i += 512) {
      int row = i >> 2, part = i & 3;
      *(bf16x8*)&B2[row * 40 + part * 8] = rB[c++];
    }
    waitl0();
    __builtin_amdgcn_s_barrier();
  }
  for (int kt = 0; kt < KT; ++kt) {
    const int kb = kt << 5;
    bf16x8 af[8], bfr[NF2];
#pragma unroll
    for (int m = 0; m < 8; ++m) {
      int row = (wr << 7) + (m << 4) + lr;
      af[m] = *(const bf16x8*)&hT[HIDX(row, kb + lk)];
    }
#pragma unroll
    for (int n = 0; n < NF2; ++n) {
      int cc = wc * (NF2 * 16) + (n << 4) + lr;
      bfr[n] = *(const bf16x8*)&B2[cc * 40 + lk];
    }
    bf16x8 rN[NCH];
    if (kt + 1 < KT) {
      int c = 0;
      for (int i = tid; i < M2 * 4; i += 512) {
        int row = i >> 2, part = i & 3;
        rN[c++] = *(const bf16x8*)(Wsrc + (size_t)row * KK + kb + 32 + part * 8);
      }
    }
#pragma unroll
    for (int m = 0; m < 8; ++m)
#pragma unroll
      for (int n = 0; n < NF2; ++n)
        acc[m][n] = __builtin_amdgcn_mfma_f32_16x16x32_bf16(af[m], bfr[n], acc[m][n], 0, 0, 0);
    __builtin_amdgcn_s_barrier();           // all waves done reading B2
    if (kt + 1 < KT) {
      waitv<0>();
      int c = 0;
      for (int i = tid; i < M2 * 4; i += 512) {
        int row = i >> 2, part = i & 3;
        *(bf16x8*)&B2[row * 40 + part * 8] = rN[c++];
      }
      waitl0();
    }
    __builtin_amdgcn_s_barrier();           // B2 ready for next step
  }
}

// ---------------- evo mega-kernel: h1->h2->h3->h4 -> {out_evo, pre1+stats} ----------------
__global__ __launch_bounds__(512) void k_evochain(const u16* __restrict__ eW2b, const u16* __restrict__ eW3b,
                                                  const u16* __restrict__ eW4b, const u16* __restrict__ wTail,
                                                  const u16* __restrict__ Qo, const u16* __restrict__ Qd,
                                                  const int* __restrict__ od, const float* __restrict__ distb,
                                                  const float* __restrict__ w512, const u16* __restrict__ sbuf,
                                                  float* __restrict__ oevo, u16* __restrict__ opre,
                                                  float* __restrict__ stats) {
  __shared__ alignas(16) u16 hT[65536];    // 128KB: stage1 dbufs alias [0,32768); h-tiles after
  __shared__ alignas(16) u16 B2[12800];    // 25.6KB, row stride 40 u16 (bank-phase 2-way free)
  __shared__ alignas(16) float sAux[1024]; // 4KB: sW | sDist | sO | sD
  const int tid = threadIdx.x;
  const int lane = tid & 63;
  const int w = tid >> 6;
  const int wr = w >> 2, wc = w & 3;
  const size_t rowBase = (size_t)blockIdx.x * 256;
  const int crow = lane >> 2, ccol = (lane & 3) << 3;
  const int arow = tid >> 1, acol = (tid & 1) << 4;
  const int lr = lane & 15, lk = (lane >> 4) << 3, lg = lane >> 4;

  float* sW = sAux;
  float* sDist = sAux + 256;
  int* sO = (int*)(sAux + 512);
  int* sD = (int*)(sAux + 768);

  if (tid < 256) {
    int2 p = ((const int2*)od)[rowBase + tid];
    sO[tid] = p.x; sD[tid] = p.y;
    sDist[tid] = distb[rowBase + tid];
    sW[tid] = w512[tid];
  }
  __syncthreads();

  // ======== stage 1: h2 = lrelu(h1 @ eW2^T), h1 built from Q tables (proven evo loop) ========
  {
    u16* A0 = hT;            // [2][8192]
    u16* B0 = hT + 16384;    // [2][8192]
    auto stageB = [&](int buf, int kb) {
#pragma unroll
      for (int i = 0; i < 2; ++i) {
        int c = w * 2 + i;
        const u16* src = eW2b + (size_t)((c << 4) + crow) * 256 + kb + ccol;
        g2lds16(src, B0 + buf * 8192 + (c << 9));
      }
    };
    auto loadA = [&](int kb, bf16x8& r0, bf16x8& r1, bf16x8& r2, bf16x8& r3) {
      const u16* qo = Qo + (size_t)sO[arow] * 256 + kb + acol;
      const u16* qd = Qd + (size_t)sD[arow] * 256 + kb + acol;
      r0 = *(const bf16x8*)qo; r1 = *(const bf16x8*)(qo + 8);
      r2 = *(const bf16x8*)qd; r3 = *(const bf16x8*)(qd + 8);
    };
    auto writeA = [&](int buf, int kb, bf16x8 r0, bf16x8 r1, bf16x8 r2, bf16x8 r3) {
      float dist = sDist[arow];
      bf16x8 w0, w1;
#pragma unroll
      for (int j = 0; j < 8; ++j) {
        float v = b2f((u16)r0[j]) + b2f((u16)r2[j]) + dist * sW[kb + acol + j];
        w0[j] = (short)f2b(lrelu(v, 0.01f));
        float v2 = b2f((u16)r1[j]) + b2f((u16)r3[j]) + dist * sW[kb + acol + 8 + j];
        w1[j] = (short)f2b(lrelu(v2, 0.01f));
      }
      *(bf16x8*)(A0 + buf * 8192 + arow * 32 + acol) = w0;
      *(bf16x8*)(A0 + buf * 8192 + arow * 32 + acol + 8) = w1;
    };

    f32x4 acc[8][4];
    const f32x4 z4 = {0.f, 0.f, 0.f, 0.f};
#pragma unroll
    for (int m = 0; m < 8; ++m)
#pragma unroll
      for (int n = 0; n < 4; ++n) acc[m][n] = z4;

    bf16x8 p0, p1, p2, p3;
    {
      bf16x8 c0, c1, c2, c3;
      loadA(0, c0, c1, c2, c3);
      writeA(0, 0, c0, c1, c2, c3);
    }
    stageB(0, 0);
    fence();
    loadA(32, p0, p1, p2, p3);
    fence();
    waitv<4>();
    waitl0();
    __builtin_amdgcn_s_barrier();

    int cur = 0;
    for (int kt = 0; kt < 8; ++kt) {
      const int kb = kt << 5;
      const bool hasN = kt + 1 < 8, hasNN = kt + 2 < 8;
      bf16x8 bfr[4];
#pragma unroll
      for (int n = 0; n < 4; ++n)
        bfr[n] = *(const bf16x8*)(B0 + cur * 8192 + ((((wc << 2) + n) << 4) + lr) * 32 + lk);
      if (hasN) stageB(cur ^ 1, kb + 32);
      fence();
      bf16x8 q0, q1, q2, q3;
      if (hasNN) loadA(kb + 64, q0, q1, q2, q3);
      fence();
#pragma unroll
      for (int m = 0; m < 8; ++m) {
        bf16x8 af = *(const bf16x8*)(A0 + cur * 8192 + (((wr << 7) + (m << 4) + lr) << 5) + lk);
#pragma unroll
        for (int n = 0; n < 4; ++n)
          acc[m][n] = __builtin_amdgcn_mfma_f32_16x16x32_bf16(af, bfr[n], acc[m][n], 0, 0, 0);
      }
      if (hasN) {
        if (hasNN) waitv<6>(); else waitv<2>();
        writeA(cur ^ 1, kb + 32, p0, p1, p2, p3);
        p0 = q0; p1 = q1; p2 = q2; p3 = q3;
        if (hasNN) waitv<4>(); else waitv<0>();
        waitl0();
      }
      __builtin_amdgcn_s_barrier();
      cur ^= 1;
    }
    // write h2 into hT (swizzled), lrelu applied
#pragma unroll
    for (int m = 0; m < 8; ++m)
#pragma unroll
      for (int n = 0; n < 4; ++n) {
        const int col = (wc << 6) + (n << 4) + lr;
#pragma unroll
        for (int j = 0; j < 4; ++j) {
          const int row = (wr << 7) + (m << 4) + (lg << 2) + j;
          float v = acc[m][n][j];
          v = v > 0.f ? v : v * 0.01f;
          hT[HIDX(row, col)] = f2b(v);
        }
      }
    waitl0();
    __builtin_amdgcn_s_barrier();
  }

  // ======== stage 2: h3 = lrelu(h2 @ eW3^T), K=256 M=256 ========
  {
    f32x4 acc[8][4];
    const f32x4 z4 = {0.f, 0.f, 0.f, 0.f};
#pragma unroll
    for (int m = 0; m < 8; ++m)
#pragma unroll
      for (int n = 0; n < 4; ++n) acc[m][n] = z4;
    fusedStage<4, 256, 256>(eW3b, hT, B2, tid, acc);
    // overwrite hT with h3
#pragma unroll
    for (int m = 0; m < 8; ++m)
#pragma unroll
      for (int n = 0; n < 4; ++n) {
        const int col = (wc << 6) + (n << 4) + lr;
#pragma unroll
        for (int j = 0; j < 4; ++j) {
          const int row = (wr << 7) + (m << 4) + (lg << 2) + j;
          float v = acc[m][n][j];
          v = v > 0.f ? v : v * 0.01f;
          hT[HIDX(row, col)] = f2b(v);
        }
      }
    waitl0();
    __builtin_amdgcn_s_barrier();
  }

  // ======== stage 3: h4 = lrelu(h3 @ eW4^T), K=256 M=128; then hS = [h4|S|0] ========
  {
    f32x4 acc[8][2];
    const f32x4 z4 = {0.f, 0.f, 0.f, 0.f};
#pragma unroll
    for (int m = 0; m < 8; ++m)
#pragma unroll
      for (int n = 0; n < 2; ++n) acc[m][n] = z4;
    fusedStage<2, 256, 128>(eW4b, hT, B2, tid, acc);
#pragma unroll
    for (int m = 0; m < 8; ++m)
#pragma unroll
      for (int n = 0; n < 2; ++n) {
        const int col = (wc << 5) + (n << 4) + lr;
#pragma unroll
        for (int j = 0; j < 4; ++j) {
          const int row = (wr << 7) + (m << 4) + (lg << 2) + j;
          float v = acc[m][n][j];
          v = v > 0.f ? v : v * 0.01f;
          hT[HIDX(row, col)] = f2b(v);
        }
      }
    // S columns (128..135 incl. zeros) + zero pad (136..159)
    if (tid < 256) {
      bf16x8 s8 = *(const bf16x8*)(sbuf + (rowBase + tid) * 8);
      *(bf16x8*)&hT[HIDX(tid, 128)] = s8;
      bf16x8 z = {0, 0, 0, 0, 0, 0, 0, 0};
      *(bf16x8*)&hT[HIDX(tid, 136)] = z;
      *(bf16x8*)&hT[HIDX(tid, 144)] = z;
      *(bf16x8*)&hT[HIDX(tid, 152)] = z;
    }
    waitl0();
    __builtin_amdgcn_s_barrier();
  }

  // ======== stage 4: [out_evo | pre1+stats] = hS @ wTail^T, K=160 M=320 ========
  {
    f32x4 acc[8][5];
    const f32x4 z4 = {0.f, 0.f, 0.f, 0.f};
#pragma unroll
    for (int m = 0; m < 8; ++m)
#pragma unroll
      for (int n = 0; n < 5; ++n) acc[m][n] = z4;
    fusedStage<5, 160, 320>(wTail, hT, B2, tid, acc);

    float csm[5], cq[5];
#pragma unroll
    for (int n = 0; n < 5; ++n) { csm[n] = 0.f; cq[n] = 0.f; }
#pragma unroll
    for (int m = 0; m < 8; ++m) {
#pragma unroll
      for (int n = 0; n < 5; ++n) {
        const int col = wc * 80 + (n << 4) + lr;
#pragma unroll
        for (int j = 0; j < 4; ++j) {
          const size_t row = rowBase + (wr << 7) + (m << 4) + (lg << 2) + j;
          float v = acc[m][n][j];
          if (col < 64) {
            oevo[row * 64 + col] = v;
          } else {
            opre[row * 256 + (col - 64)] = f2b(v);
            csm[n] += v; cq[n] += v * v;
          }
        }
      }
    }
    const int shard = ((int)blockIdx.x & 7) * SHST;
#pragma unroll
    for (int n = 0; n < 5; ++n) {
      float s = csm[n], q = cq[n];
      s += __shfl_xor(s, 16); s += __shfl_xor(s, 32);
      q += __shfl_xor(q, 16); q += __shfl_xor(q, 32);
      if (lane < 16) {
        const int col = wc * 80 + (n << 4) + lane;
        if (col >= 64) {
          atomicAdd(&stats[shard + col - 64], s);
          atomicAdd(&stats[shard + 256 + col - 64], q);
        }
      }
    }
  }
}

// ---------------- 256-row MFMA GEMM (flow layers; gload_lds dbuf, sharded stats) ----------------
template <int NF, int EPI, int BNA>
__global__ __launch_bounds__(512) void gemm256(const u16* __restrict__ A, const u16* __restrict__ W,
                                               int K, size_t lda,
                                               u16* __restrict__ obf, int ld_bf,
                                               float* __restrict__ stats,
                                               const float* __restrict__ stin, const float* __restrict__ gg,
                                               const float* __restrict__ bb, float invB) {
  constexpr int M = NF * 64;
  constexpr int CPW = 2 + NF / 2;
  __shared__ alignas(16) u16 Alds[2][256 * 32];
  __shared__ alignas(16) u16 Blds[2][M * 32];
  __shared__ float sS[256], sT[256];
  const int tid = threadIdx.x;
  const int lane = tid & 63;
  const int w = tid >> 6;
  const int wr = w >> 2, wc = w & 3;
  const size_t rowBase = (size_t)blockIdx.x * 256;

  if (BNA) {
    for (int c = tid; c < K; c += 512) {
      float s0 = 0.f, q0 = 0.f;
#pragma unroll
      for (int sh = 0; sh < 8; ++sh) {
        s0 += stin[sh * SHST + c];
        q0 += stin[sh * SHST + K + c];
      }
      float mu = s0 * invB;
      float var = q0 * invB - mu * mu;
      float sc = rsqrtf(var + 1e-5f) * gg[c];
      sS[c] = sc;
      sT[c] = bb[c] - mu * sc;
    }
    __syncthreads();
  }

  f32x4 acc[8][NF];
  const f32x4 z4 = {0.f, 0.f, 0.f, 0.f};
#pragma unroll
  for (int m = 0; m < 8; ++m)
#pragma unroll
    for (int n = 0; n < NF; ++n) acc[m][n] = z4;

  const int crow = lane >> 2;
  const int ccol = (lane & 3) << 3;
  const int KT = K >> 5;

  auto stage = [&](int buf, int kb) {
#pragma unroll
    for (int i = 0; i < CPW; ++i) {
      const int c = w * CPW + i;
      if (c < 16) {
        const u16* src = A + (rowBase + (c << 4) + crow) * lda + kb + ccol;
        g2lds16(src, &Alds[buf][(c << 4) << 5]);
      } else {
        const u16* src = W + (size_t)(((c - 16) << 4) + crow) * K + kb + ccol;
        g2lds16(src, &Blds[buf][((c - 16) << 4) << 5]);
      }
    }
  };

  stage(0, 0);
  int cur = 0;
  const int lr = lane & 15, lk = (lane >> 4) << 3, lg = lane >> 4;
  for (int kt = 0; kt < KT; ++kt) {
    const int kb = kt << 5;
    if (kt + 1 < KT) {
      stage(cur ^ 1, kb + 32);
      if constexpr (NF == 4)
        asm volatile("s_waitcnt vmcnt(4)" ::: "memory");
      else
        asm volatile("s_waitcnt vmcnt(3)" ::: "memory");
    } else {
      asm volatile("s_waitcnt vmcnt(0)" ::: "memory");
    }
    __builtin_amdgcn_s_barrier();

    float sv[8], tv[8];
    if (BNA) {
      float4 s0 = *(const float4*)&sS[kb + lk];
      float4 s1 = *(const float4*)&sS[kb + lk + 4];
      float4 t0 = *(const float4*)&sT[kb + lk];
      float4 t1 = *(const float4*)&sT[kb + lk + 4];
      sv[0] = s0.x; sv[1] = s0.y; sv[2] = s0.z; sv[3] = s0.w;
      sv[4] = s1.x; sv[5] = s1.y; sv[6] = s1.z; sv[7] = s1.w;
      tv[0] = t0.x; tv[1] = t0.y; tv[2] = t0.z; tv[3] = t0.w;
      tv[4] = t1.x; tv[5] = t1.y; tv[6] = t1.z; tv[7] = t1.w;
    }
    bf16x8 bfr[NF];
#pragma unroll
    for (int n = 0; n < NF; ++n)
      bfr[n] = *(const bf16x8*)&Blds[cur][((((wc * NF + n) << 4) + lr) << 5) + lk];
#pragma unroll
    for (int m = 0; m < 8; ++m) {
      bf16x8 af = *(const bf16x8*)&Alds[cur][(((wr << 7) + (m << 4) + lr) << 5) + lk];
      if (BNA) {
        bf16x8 o;
#pragma unroll
        for (int j = 0; j < 8; ++j) {
          float v = fmaf(b2f((u16)af[j]), sv[j], tv[j]);
          v = v > 0.f ? v : v * 0.01f;
          o[j] = (short)f2b(v);
        }
        af = o;
      }
#pragma unroll
      for (int n = 0; n < NF; ++n)
        acc[m][n] = __builtin_amdgcn_mfma_f32_16x16x32_bf16(af, bfr[n], acc[m][n], 0, 0, 0);
    }
    __builtin_amdgcn_s_barrier();
    cur ^= 1;
  }

  float csm[NF], cq[NF];
#pragma unroll
  for (int n = 0; n < NF; ++n) { csm[n] = 0.f; cq[n] = 0.f; }
#pragma unroll
  for (int m = 0; m < 8; ++m) {
#pragma unroll
    for (int n = 0; n < NF; ++n) {
      const int col = wc * (NF * 16) + (n << 4) + lr;
#pragma unroll
      for (int j = 0; j < 4; ++j) {
        const size_t row = rowBase + (wr << 7) + (m << 4) + (lg << 2) + j;
        float v = acc[m][n][j];
        if (EPI == 0) {
          v = v > 0.f ? v : v * 0.01f;
          obf[row * ld_bf + col] = f2b(v);
        } else {
          obf[row * ld_bf + col] = f2b(v);
          csm[n] += v; cq[n] += v * v;
        }
      }
    }
  }
  if (EPI == 1) {
    const int shard = ((int)blockIdx.x & 7) * SHST;
#pragma unroll
    for (int n = 0; n < NF; ++n) {
      float s = csm[n], q = cq[n];
      s += __shfl_xor(s, 16); s += __shfl_xor(s, 32);
      q += __shfl_xor(q, 16); q += __shfl_xor(q, 32);
      if (lane < 16) {
        const int col = wc * (NF * 16) + (n << 4) + lane;
        atomicAdd(&stats[shard + col], s);
        atomicAdd(&stats[shard + M + col], q);
      }
    }
  }
}

// ---------------- fused BN4 + final dot (sharded stats) ----------------
__global__ __launch_bounds__(256) void k_fout4(const u16* __restrict__ pre, const float* __restrict__ st,
                                               const float* __restrict__ g, const float* __restrict__ b,
                                               const float* __restrict__ W, float* __restrict__ out,
                                               float invB) {
  __shared__ float smu[128], srs[128], sg[128], sb[128], sw[128];
  if (threadIdx.x < 128) {
    int c = threadIdx.x;
    float s0 = 0.f, q0 = 0.f;
#pragma unroll
    for (int sh = 0; sh < 8; ++sh) {
      s0 += st[sh * SHST + c];
      q0 += st[sh * SHST + 128 + c];
    }
    float mu = s0 * invB;
    float var = q0 * invB - mu * mu;
    smu[c] = mu;
    srs[c] = rsqrtf(var + 1e-5f);
    sg[c] = g[c];
    sb[c] = b[c];
    sw[c] = W[c];
  }
  __syncthreads();
  int bi = blockIdx.x * 256 + threadIdx.x;
  const u16* hp = pre + (size_t)bi * 128;
  float acc = 0.f;
#pragma unroll
  for (int k = 0; k < 128; k += 8) {
    bf16x8 u = *(const bf16x8*)(hp + k);
#pragma unroll
    for (int j = 0; j < 8; ++j) {
      int c = k + j;
      float v = (b2f((u16)u[j]) - smu[c]) * srs[c] * sg[c] + sb[c];
      v = b2f(f2b(lrelu(v, 0.01f)));
      acc += v * sw[c];
    }
  }
  out[bi] = acc;
}

// ---------------- launch ----------------
extern "C" void kernel_launch(void* const* d_in, const int* in_sizes, int n_in,
                              void* d_out, int out_size, void* d_ws, size_t ws_size,
                              hipStream_t stream) {
  (void)in_sizes; (void)n_in; (void)out_size; (void)ws_size;

  const float* x0 = (const float*)d_in[0];
  const int* ei0 = (const int*)d_in[1];
  const float* ea0 = (const float*)d_in[2];
  const float* x1 = (const float*)d_in[3];
  const int* ei1 = (const int*)d_in[4];
  const float* ea1 = (const float*)d_in[5];
  const float* dm = (const float*)d_in[6];
  const float* nv = (const float*)d_in[7];
  const int* od = (const int*)d_in[8];
  const float* Wl0 = (const float*)d_in[9];
  const float* bl0 = (const float*)d_in[10];
  const float* Wr0 = (const float*)d_in[11];
  const float* br0 = (const float*)d_in[12];
  const float* We0 = (const float*)d_in[13];
  const float* att0 = (const float*)d_in[14];
  const float* bia0 = (const float*)d_in[15];
  const float* Wl1 = (const float*)d_in[16];
  const float* bl1 = (const float*)d_in[17];
  const float* Wr1 = (const float*)d_in[18];
  const float* br1 = (const float*)d_in[19];
  const float* We1 = (const float*)d_in[20];
  const float* att1 = (const float*)d_in[21];
  const float* bia1 = (const float*)d_in[22];
  const float* eW1 = (const float*)d_in[23];
  const float* eW2 = (const float*)d_in[24];
  const float* eW3 = (const float*)d_in[25];
  const float* eW4 = (const float*)d_in[26];
  const float* eWo = (const float*)d_in[27];
  const float* fW1 = (const float*)d_in[28];
  const float* fW2 = (const float*)d_in[29];
  const float* fW3 = (const float*)d_in[30];
  const float* fW4 = (const float*)d_in[31];
  const float* fWo = (const float*)d_in[32];
  const float* fg[4] = {(const float*)d_in[33], (const float*)d_in[35], (const float*)d_in[37], (const float*)d_in[39]};
  const float* fb[4] = {(const float*)d_in[34], (const float*)d_in[36], (const float*)d_in[38], (const float*)d_in[40]};

  float* out_inf = (float*)d_out;
  float* out_a1 = out_inf + NB;
  float* out_a2 = out_a1 + (size_t)ET * 4;
  float* out_evo = out_a2 + (size_t)ET * 4;

  // ---- workspace carve ----
  char* base = (char*)d_ws;
  size_t cur = 0;
  auto carve = [&](size_t bytes) -> char* {
    char* p = base + cur;
    cur += (bytes + 255) & ~(size_t)255;
    return p;
  };
  u16* bufA = (u16*)carve((size_t)NB * 256 * 2);
  u16* bufB = (u16*)carve((size_t)NB * 256 * 2);
  u16* sbuf = (u16*)carve((size_t)NB * 8 * 2);
  float* n1 = (float*)carve((size_t)NN * 128 * 4);
  float* n2 = (float*)carve((size_t)NN * 128 * 4);
  u16* Qob = (u16*)carve((size_t)NN * 256 * 2);
  u16* Qdb = (u16*)carve((size_t)NN * 256 * 2);
  float* xl = (float*)carve((size_t)2 * NN * 128 * 4);
  float* xr = (float*)carve((size_t)2 * NN * 128 * 4);
  float* stats = (float*)carve((size_t)8 * SHST * 4);
  int* cw = (int*)carve((size_t)4 * NN * 4);
  int* cnt = cw;
  int* wr = cw + 2 * NN;
  int* cs = (int*)carve((size_t)2 * (NN + 1) * 4);
  int2* csr = (int2*)carve((size_t)2 * ET * 8);
  float* m_out = (float*)carve((size_t)2 * NN * 4 * 4);
  float* den_out = (float*)carve((size_t)2 * NN * 4 * 4);
  float* asum = (float*)carve((size_t)2 * NN * 8 * 4);
  float* scr = (float*)carve((size_t)2 * ET * 4 * 4);
  float* distb = (float*)carve((size_t)NB * 4);
  float* w512 = (float*)carve(1024);
  float* W1T = (float*)carve(512 * 256 * 4);
  float* st[4] = {stats, stats + 512, stats + 1024, stats + 1536};
  u16* eW2b = (u16*)carve(256 * 256 * 2);
  u16* eW3b = (u16*)carve(256 * 256 * 2);
  u16* eW4b = (u16*)carve(128 * 256 * 2);
  u16* fW2b = (u16*)carve(256 * 256 * 2);
  u16* fW3b = (u16*)carve(256 * 256 * 2);
  u16* fW4b = (u16*)carve(128 * 256 * 2);
  u16* wTail = (u16*)carve(320 * 160 * 2);

  // ---- prep ----
  k_prep<<<1833, 256, 0, stream>>>(eW2, eW3, eW4, eWo, fW1, fW2, fW3, fW4, eW1,
                                   eW2b, eW3b, eW4b, fW2b, fW3b, fW4b,
                                   W1T, w512, wTail);
  hipMemsetAsync(stats, 0, (size_t)8 * SHST * 4 + (size_t)4 * NN * 4, stream);
  k_sprep<<<NB / 256, 256, 0, stream>>>(od, dm, nv, distb, sbuf);

  // ---- GATv2 x2, batched ----
  k_count2<<<(2 * ET + 255) / 256, 256, 0, stream>>>(ei0, ei1, cnt);
  k_scan2<<<2, 1024, 0, stream>>>(cnt, cs);
  k_fill2<<<(2 * ET + 255) / 256, 256, 0, stream>>>(ei0, ei1, cs, wr, csr);
  k_asum2<<<2 * NN / 4, 256, 0, stream>>>(csr, cs, ea0, ea1, asum);
  k_xlr2<<<NN, 256, 0, stream>>>(x0, x1, Wl0, bl0, Wr0, br0, Wl1, bl1, Wr1, br1, xl, xr);
  k_scr2<<<4096, 256, 0, stream>>>(xl, xr, ei0, ei1, ea0, ea1, asum, We0, We1, att0, att1, scr);
  k_nodered2<<<2 * NN / 4, 256, 0, stream>>>(scr, csr, cs, xl, bia0, bia1, m_out, den_out, n1, n2);
  k_alpha2<<<(2 * ET * 4 + 255) / 256, 256, 0, stream>>>(scr, ei0, ei1, m_out, den_out, out_a1, out_a2);

  // ---- evo ----
  k_qtab<<<NN / 16, 256, 0, stream>>>(n1, n2, W1T, Qob, Qdb);

  const float invB = 1.0f / (float)NB;
  const int GB = NB / 256;
  // fused evo chain: h1->h2->h3->h4 -> out_evo + pre1(bufA) + st[0]
  k_evochain<<<GB, 512, 0, stream>>>(eW2b, eW3b, eW4b, wTail, Qob, Qdb, od, distb, w512, sbuf,
                                     out_evo, bufA, st[0]);

  // ---- flow (BN fused into consumer GEMMs; sharded stats) ----
  gemm256<4, 1, 1><<<GB, 512, 0, stream>>>(bufA, fW2b, 256, 256, bufB, 256, st[1],
                                           st[0], fg[0], fb[0], invB);
  gemm256<4, 1, 1><<<GB, 512, 0, stream>>>(bufB, fW3b, 256, 256, bufA, 256, st[2],
                                           st[1], fg[1], fb[1], invB);
  gemm256<2, 1, 1><<<GB, 512, 0, stream>>>(bufA, fW4b, 256, 256, bufB, 128, st[3],
                                           st[2], fg[2], fb[2], invB);
  k_fout4<<<NB / 256, 256, 0, stream>>>(bufB, st[3], fg[3], fb[3], fWo, out_inf, invB);
}

// Round 11
// 1247.515 us; speedup vs baseline: 1.4412x; 1.4412x over previous
//
#include <hip/hip_runtime.h>

typedef unsigned short u16;
typedef unsigned int u32;

#define NN 10000      // nodes
#define NE 320000     // edges
#define ET 330000     // edges + self loops
#define NB 262144     // batch
#define SHST 1792     // stats shard stride (floats)

typedef __attribute__((ext_vector_type(8))) short bf16x8;
typedef __attribute__((ext_vector_type(4))) float f32x4;

__device__ __forceinline__ u16 f2b(float f) {
  u32 u = __float_as_uint(f);
  u += 0x7fffu + ((u >> 16) & 1u);
  return (u16)(u >> 16);
}
__device__ __forceinline__ float b2f(u16 h) {
  return __uint_as_float(((u32)h) << 16);
}
__device__ __forceinline__ float lrelu(float v, float s) { return v > 0.f ? v : v * s; }

__device__ __forceinline__ void g2lds16(const void* g, void* l) {
  __builtin_amdgcn_global_load_lds((const __attribute__((address_space(1))) void*)g,
                                   (__attribute__((address_space(3))) void*)l, 16, 0, 0);
}

template <int N> __device__ __forceinline__ void waitv() {
  if constexpr (N == 0) asm volatile("s_waitcnt vmcnt(0)" ::: "memory");
  else if constexpr (N == 1) asm volatile("s_waitcnt vmcnt(1)" ::: "memory");
  else if constexpr (N == 2) asm volatile("s_waitcnt vmcnt(2)" ::: "memory");
  else if constexpr (N == 3) asm volatile("s_waitcnt vmcnt(3)" ::: "memory");
  else if constexpr (N == 4) asm volatile("s_waitcnt vmcnt(4)" ::: "memory");
  else if constexpr (N == 5) asm volatile("s_waitcnt vmcnt(5)" ::: "memory");
  else asm volatile("s_waitcnt vmcnt(6)" ::: "memory");
}
__device__ __forceinline__ void waitl0() { asm volatile("s_waitcnt lgkmcnt(0)" ::: "memory"); }
__device__ __forceinline__ void fence() { asm volatile("" ::: "memory"); }

// ---------------- merged prep ----------------
__global__ __launch_bounds__(256) void k_prep(const float* __restrict__ eW2, const float* __restrict__ eW3,
                                              const float* __restrict__ eW4, const float* __restrict__ eWo,
                                              const float* __restrict__ fW1, const float* __restrict__ fW2,
                                              const float* __restrict__ fW3, const float* __restrict__ fW4,
                                              const float* __restrict__ eW1,
                                              u16* eW2b, u16* eW3b, u16* eW4b,
                                              u16* fW2b, u16* fW3b, u16* fW4b,
                                              float* W1T, float* w512, u16* wTail) {
  const int blk = blockIdx.x, tid = threadIdx.x;
  if (blk < 256) {
    int t = blk * 256 + tid; eW2b[t] = f2b(eW2[t]);
  } else if (blk < 512) {
    int t = (blk - 256) * 256 + tid; eW3b[t] = f2b(eW3[t]);
  } else if (blk < 640) {
    int t = (blk - 512) * 256 + tid; eW4b[t] = f2b(eW4[t]);
  } else if (blk < 896) {
    int t = (blk - 640) * 256 + tid; fW2b[t] = f2b(fW2[t]);
  } else if (blk < 1152) {
    int t = (blk - 896) * 256 + tid; fW3b[t] = f2b(fW3[t]);
  } else if (blk < 1280) {
    int t = (blk - 1152) * 256 + tid; fW4b[t] = f2b(fW4[t]);
  } else if (blk < 1536) {
    int m = blk - 1280;
    for (int k = tid; k < 512; k += 256) W1T[(size_t)k * 256 + m] = eW1[(size_t)m * 513 + k];
  } else if (blk == 1536) {
    w512[tid] = eW1[(size_t)tid * 513 + 512];
  } else if (blk < 1577) {
    int t = (blk - 1537) * 256 + tid;   // 64 rows x 160
    int r = t / 160, k = t - r * 160;
    wTail[(size_t)r * 160 + k] = (k < 128) ? f2b(eWo[(size_t)r * 128 + k]) : (u16)0;
  } else {
    int m = blk - 1577;   // row 64+m
    int k = tid;
    if (k < 160) {
      float v = 0.f;
      if (k < 128) {
        const float* fr = fW1 + (size_t)m * 69;
        for (int j = 0; j < 64; ++j) v += fr[j] * eWo[(size_t)j * 128 + k];
      } else if (k < 133) {
        v = fW1[(size_t)m * 69 + 64 + (k - 128)];
      }
      wTail[(size_t)(64 + m) * 160 + k] = f2b(v);
    }
  }
}

// distb + S columns (128..159) of bufC
__global__ __launch_bounds__(256) void k_sprep(const int* __restrict__ od, const float* __restrict__ dm,
                                               const float* __restrict__ nv,
                                               float* __restrict__ distb, u16* __restrict__ bufC) {
  int b = blockIdx.x * 256 + threadIdx.x;
  int o = od[b * 2], d = od[b * 2 + 1];
  float dist = dm[(size_t)o * NN + d];
  distb[b] = dist;
  u16 tmp[32];
  tmp[0] = f2b(nv[o * 2]);
  tmp[1] = f2b(nv[d * 2]);
  tmp[2] = f2b(nv[o * 2 + 1]);
  tmp[3] = f2b(nv[d * 2 + 1]);
  tmp[4] = f2b(dist);
#pragma unroll
  for (int k = 5; k < 32; ++k) tmp[k] = 0;
  u16* p = bufC + (size_t)b * 160 + 128;
#pragma unroll
  for (int k = 0; k < 4; ++k) *(bf16x8*)(p + k * 8) = *(bf16x8*)(tmp + k * 8);
}

// ---------------- dual-graph CSR build ----------------
__global__ __launch_bounds__(256) void k_count2(const int* __restrict__ ei0, const int* __restrict__ ei1,
                                                int* __restrict__ cnt) {
  int t = blockIdx.x * 256 + threadIdx.x;
  if (t >= 2 * ET) return;
  int g = t >= ET; int e = t - g * ET;
  const int* ei = g ? ei1 : ei0;
  int d = (e < NE) ? ei[NE + e] : (e - NE);
  atomicAdd(&cnt[g * NN + d], 1);
}

__global__ __launch_bounds__(1024) void k_scan2(const int* __restrict__ cnt, int* __restrict__ cs) {
  const int g = blockIdx.x;
  cnt += g * NN; cs += g * (NN + 1);
  __shared__ int part[1024];
  int tid = threadIdx.x;
  int base = tid * 10;
  int local[10];
  int s = 0;
#pragma unroll
  for (int i = 0; i < 10; ++i) {
    int idx = base + i;
    int v = (idx < NN) ? cnt[idx] : 0;
    local[i] = s; s += v;
  }
  part[tid] = s;
  __syncthreads();
  for (int off = 1; off < 1024; off <<= 1) {
    int v = (tid >= off) ? part[tid - off] : 0;
    __syncthreads();
    part[tid] += v;
    __syncthreads();
  }
  int pre = (tid > 0) ? part[tid - 1] : 0;
#pragma unroll
  for (int i = 0; i < 10; ++i) {
    int idx = base + i;
    if (idx < NN) cs[idx] = pre + local[i];
  }
  if (tid == 1023) cs[NN] = part[1023];
}

__global__ __launch_bounds__(256) void k_fill2(const int* __restrict__ ei0, const int* __restrict__ ei1,
                                               const int* __restrict__ cs, int* __restrict__ wr,
                                               int2* __restrict__ csr) {
  int t = blockIdx.x * 256 + threadIdx.x;
  if (t >= 2 * ET) return;
  int g = t >= ET; int e = t - g * ET;
  const int* ei = g ? ei1 : ei0;
  int s, d;
  if (e < NE) { s = ei[e]; d = ei[NE + e]; } else { s = e - NE; d = s; }
  int pos = atomicAdd(&wr[g * NN + d], 1);
  csr[(size_t)g * ET + cs[g * (NN + 1) + d] + pos] = make_int2(e, s);
}

__global__ __launch_bounds__(256) void k_asum2(const int2* __restrict__ csr, const int* __restrict__ cs,
                                               const float* __restrict__ ea0, const float* __restrict__ ea1,
                                               float* __restrict__ asum) {
  int wid = (blockIdx.x * 256 + threadIdx.x) >> 6;   // 0..2*NN-1
  int lane = threadIdx.x & 63;
  int g = wid >= NN; int n = wid - g * NN;
  const float* ea = g ? ea1 : ea0;
  const int* csg = cs + g * (NN + 1);
  const int2* csrg = csr + (size_t)g * ET;
  int beg = csg[n], end = csg[n + 1];
  int j = lane & 7, slot = lane >> 3;
  float acc = 0.f;
  for (int i = beg + slot; i < end; i += 8) {
    int e = csrg[i].x;
    if (e < NE) acc += ea[(size_t)e * 8 + j];
  }
  acc += __shfl_xor(acc, 8);
  acc += __shfl_xor(acc, 16);
  acc += __shfl_xor(acc, 32);
  if (lane < 8) {
    float dr = (float)(end - beg - 1);
    asum[(size_t)wid * 8 + lane] = acc / fmaxf(dr, 1.f);
  }
}

// ---------------- dual-graph GAT ----------------
__global__ __launch_bounds__(256) void k_xlr2(const float* __restrict__ x0, const float* __restrict__ x1,
                                              const float* __restrict__ Wl0, const float* __restrict__ bl0,
                                              const float* __restrict__ Wr0, const float* __restrict__ br0,
                                              const float* __restrict__ Wl1, const float* __restrict__ bl1,
                                              const float* __restrict__ Wr1, const float* __restrict__ br1,
                                              float* __restrict__ xl, float* __restrict__ xr) {
  const int g = blockIdx.x >= NN / 2;
  const int lb = blockIdx.x - g * (NN / 2);
  const float* x = g ? x1 : x0;
  const float* Wl = g ? Wl1 : Wl0;
  const float* bl = g ? bl1 : bl0;
  const float* Wr = g ? Wr1 : Wr0;
  const float* br = g ? br1 : br0;
  xl += (size_t)g * NN * 128; xr += (size_t)g * NN * 128;
  __shared__ float sx[128];
  int nb = lb * 2;
  for (int i = threadIdx.x; i < 128; i += 256) sx[i] = x[(size_t)nb * 64 + i];
  __syncthreads();
  int half = threadIdx.x >> 7;
  int node = nb + half;
  int m = threadIdx.x & 127;
  const float* xv = sx + (half << 6);
  float al = bl[m], ar = br[m];
  const float* wl = Wl + (size_t)m * 64;
  const float* wr = Wr + (size_t)m * 64;
#pragma unroll 8
  for (int k = 0; k < 64; ++k) { float xk = xv[k]; al += xk * wl[k]; ar += xk * wr[k]; }
  xl[(size_t)node * 128 + m] = al;
  xr[(size_t)node * 128 + m] = ar;
}

__global__ __launch_bounds__(256) void k_scr2(const float* __restrict__ xl, const float* __restrict__ xr,
                                              const int* __restrict__ ei0, const int* __restrict__ ei1,
                                              const float* __restrict__ ea0, const float* __restrict__ ea1,
                                              const float* __restrict__ asum,
                                              const float* __restrict__ We0, const float* __restrict__ We1,
                                              const float* __restrict__ att0, const float* __restrict__ att1,
                                              float* __restrict__ scr) {
  const int g = blockIdx.x >= 2048;
  const int lb = blockIdx.x - g * 2048;
  const int* ei = g ? ei1 : ei0;
  const float* ea = g ? ea1 : ea0;
  const float* We = g ? We1 : We0;
  const float* att = g ? att1 : att0;
  const float* mattr = asum + (size_t)g * NN * 8;
  const float* xlg = xl + (size_t)g * NN * 128;
  const float* xrg = xr + (size_t)g * NN * 128;
  float* scrg = scr + (size_t)g * ET * 4;

  const int lane = threadIdx.x & 63;
  const int sub = lane & 31;
  const int half = lane >> 5;
  float4 w0[4], w1[4];
#pragma unroll
  for (int c = 0; c < 4; ++c) {
    const float* wp = We + (size_t)(sub * 4 + c) * 8;
    w0[c] = *(const float4*)wp;
    w1[c] = *(const float4*)(wp + 4);
  }
  const float4 attv = *(const float4*)(att + sub * 4);
  const int gw = (lb * 256 + threadIdx.x) >> 6;
  const int nw = 2048 * 4;
  for (int p = gw; p < ET / 2; p += nw) {
    int e = p * 2 + half;
    int s, d; const float* ap;
    if (e < NE) { s = ei[e]; d = ei[NE + e]; ap = ea + (size_t)e * 8; }
    else { s = e - NE; d = s; ap = mattr + (size_t)(e - NE) * 8; }
    float4 a0 = *(const float4*)ap;
    float4 a1 = *(const float4*)(ap + 4);
    float4 xlv = *(const float4*)(xlg + (size_t)s * 128 + sub * 4);
    float4 xrv = *(const float4*)(xrg + (size_t)d * 128 + sub * 4);
    const float* xle = (const float*)&xlv;
    const float* xre = (const float*)&xrv;
    const float* ate = (const float*)&attv;
    float psum = 0.f;
#pragma unroll
    for (int c = 0; c < 4; ++c) {
      float em = a0.x * w0[c].x + a0.y * w0[c].y + a0.z * w0[c].z + a0.w * w0[c].w
               + a1.x * w1[c].x + a1.y * w1[c].y + a1.z * w1[c].z + a1.w * w1[c].w;
      float v = xle[c] + xre[c] + em;
      v = v > 0.f ? v : 0.2f * v;
      psum += v * ate[c];
    }
    psum += __shfl_xor(psum, 1);
    psum += __shfl_xor(psum, 2);
    psum += __shfl_xor(psum, 4);
    if ((sub & 7) == 0) scrg[(size_t)e * 4 + (sub >> 3)] = psum;
  }
}

__global__ __launch_bounds__(256) void k_nodered2(const float* __restrict__ scr, const int2* __restrict__ csr,
                                                  const int* __restrict__ cs, const float* __restrict__ xl,
                                                  const float* __restrict__ bias0, const float* __restrict__ bias1,
                                                  float* __restrict__ m_out, float* __restrict__ den_out,
                                                  float* __restrict__ n1, float* __restrict__ n2) {
  int dd = (blockIdx.x * 256 + threadIdx.x) >> 6;   // 0..2*NN-1
  int lane = threadIdx.x & 63;
  int g = dd >= NN; int d = dd - g * NN;
  const float* scrg = scr + (size_t)g * ET * 4;
  const int2* csrg = csr + (size_t)g * ET;
  const int* csg = cs + g * (NN + 1);
  const float* xlg = xl + (size_t)g * NN * 128;
  const float* bias = g ? bias1 : bias0;
  float* mo = m_out + (size_t)g * NN * 4;
  float* dn = den_out + (size_t)g * NN * 4;
  float* nout = g ? n2 : n1;

  int h0 = lane >> 5;
  int beg = csg[d], end = csg[d + 1];
  float mx0 = -3.4e38f, mx1 = -3.4e38f;
  for (int i = beg; i < end; ++i) {
    int e = csrg[i].x;
    mx0 = fmaxf(mx0, scrg[(size_t)e * 4 + h0]);
    mx1 = fmaxf(mx1, scrg[(size_t)e * 4 + h0 + 2]);
  }
  float acc0 = 0.f, acc1 = 0.f, dn0 = 0.f, dn1 = 0.f;
  for (int i = beg; i < end; ++i) {
    int2 es = csrg[i];
    float ex0 = __expf(scrg[(size_t)es.x * 4 + h0] - mx0);
    float ex1 = __expf(scrg[(size_t)es.x * 4 + h0 + 2] - mx1);
    dn0 += ex0; dn1 += ex1;
    const float* xp = xlg + (size_t)es.y * 128;
    acc0 += ex0 * xp[lane];
    acc1 += ex1 * xp[64 + lane];
  }
  if (lane == 0 || lane == 32) {
    mo[d * 4 + h0] = mx0;     mo[d * 4 + h0 + 2] = mx1;
    dn[d * 4 + h0] = dn0;     dn[d * 4 + h0 + 2] = dn1;
  }
  nout[(size_t)d * 128 + lane] = fmaxf(acc0 / dn0 + bias[lane], 0.f);
  nout[(size_t)d * 128 + 64 + lane] = fmaxf(acc1 / dn1 + bias[64 + lane], 0.f);
}

__global__ __launch_bounds__(256) void k_alpha2(const float* __restrict__ scr,
                                                const int* __restrict__ ei0, const int* __restrict__ ei1,
                                                const float* __restrict__ m, const float* __restrict__ den,
                                                float* __restrict__ a1, float* __restrict__ a2) {
  int t = blockIdx.x * 256 + threadIdx.x;
  if (t >= 2 * ET * 4) return;
  int g = t >= ET * 4; int tt = t - g * ET * 4;
  int e = tt >> 2, h = tt & 3;
  const int* ei = g ? ei1 : ei0;
  int d = (e < NE) ? ei[NE + e] : (e - NE);
  const float* mg = m + (size_t)g * NN * 4;
  const float* dg = den + (size_t)g * NN * 4;
  float* aout = g ? a2 : a1;
  aout[tt] = __expf(scr[(size_t)g * ET * 4 + tt] - mg[d * 4 + h]) / dg[d * 4 + h];
}

// ---------------- evo L1 factorization (bf16 tables) ----------------
__global__ __launch_bounds__(256) void k_qtab(const float* __restrict__ n1, const float* __restrict__ n2,
                                              const float* __restrict__ W1T,
                                              u16* __restrict__ Qo, u16* __restrict__ Qd) {
  __shared__ float s1[2048], s2[2048];
  int nb = blockIdx.x * 16;
  for (int i = threadIdx.x; i < 2048; i += 256) {
    s1[i] = n1[(size_t)nb * 128 + i];
    s2[i] = n2[(size_t)nb * 128 + i];
  }
  __syncthreads();
  int m = threadIdx.x;
  float qo[16], qd[16];
#pragma unroll
  for (int i = 0; i < 16; ++i) { qo[i] = 0.f; qd[i] = 0.f; }
#pragma unroll 2
  for (int k = 0; k < 128; ++k) {
    float w0 = W1T[(size_t)k * 256 + m];
    float w1 = W1T[(size_t)(128 + k) * 256 + m];
    float w2 = W1T[(size_t)(256 + k) * 256 + m];
    float w3 = W1T[(size_t)(384 + k) * 256 + m];
#pragma unroll
    for (int i = 0; i < 16; ++i) {
      float a = s1[i * 128 + k], b = s2[i * 128 + k];
      qo[i] += a * w0 + b * w2;
      qd[i] += a * w1 + b * w3;
    }
  }
#pragma unroll
  for (int i = 0; i < 16; ++i) {
    Qo[(size_t)(nb + i) * 256 + m] = f2b(qo[i]);
    Qd[(size_t)(nb + i) * 256 + m] = f2b(qd[i]);
  }
}

// ---------------- 256-row MFMA GEMM (gload_lds, 2 barriers, counted vmcnt) ----------------
// stats sharded 8-way by blockIdx&7 (stride SHST); BNA consumer sums shards.
template <int NF, int EPI, int BNA>
__global__ __launch_bounds__(512) void gemm256(const u16* __restrict__ A, const u16* __restrict__ W,
                                               int K, size_t lda,
                                               u16* __restrict__ obf, int ld_bf,
                                               float* __restrict__ stats,
                                               const float* __restrict__ stin, const float* __restrict__ gg,
                                               const float* __restrict__ bb, float invB) {
  constexpr int M = NF * 64;
  constexpr int CPW = 2 + NF / 2;
  __shared__ alignas(16) u16 Alds[2][256 * 32];
  __shared__ alignas(16) u16 Blds[2][M * 32];
  __shared__ float sS[256], sT[256];
  const int tid = threadIdx.x;
  const int lane = tid & 63;
  const int w = tid >> 6;
  const int wr = w >> 2, wc = w & 3;
  const size_t rowBase = (size_t)blockIdx.x * 256;

  if (BNA) {
    for (int c = tid; c < K; c += 512) {
      float s0 = 0.f, q0 = 0.f;
#pragma unroll
      for (int sh = 0; sh < 8; ++sh) {
        s0 += stin[sh * SHST + c];
        q0 += stin[sh * SHST + K + c];
      }
      float mu = s0 * invB;
      float var = q0 * invB - mu * mu;
      float sc = rsqrtf(var + 1e-5f) * gg[c];
      sS[c] = sc;
      sT[c] = bb[c] - mu * sc;
    }
    __syncthreads();
  }

  f32x4 acc[8][NF];
  const f32x4 z4 = {0.f, 0.f, 0.f, 0.f};
#pragma unroll
  for (int m = 0; m < 8; ++m)
#pragma unroll
    for (int n = 0; n < NF; ++n) acc[m][n] = z4;

  const int crow = lane >> 2;
  const int ccol = (lane & 3) << 3;
  const int KT = K >> 5;

  auto stage = [&](int buf, int kb) {
#pragma unroll
    for (int i = 0; i < CPW; ++i) {
      const int c = w * CPW + i;
      if (c < 16) {
        const u16* src = A + (rowBase + (c << 4) + crow) * lda + kb + ccol;
        g2lds16(src, &Alds[buf][(c << 4) << 5]);
      } else {
        const u16* src = W + (size_t)(((c - 16) << 4) + crow) * K + kb + ccol;
        g2lds16(src, &Blds[buf][((c - 16) << 4) << 5]);
      }
    }
  };

  stage(0, 0);
  int cur = 0;
  const int lr = lane & 15, lk = (lane >> 4) << 3, lg = lane >> 4;
  for (int kt = 0; kt < KT; ++kt) {
    const int kb = kt << 5;
    if (kt + 1 < KT) {
      stage(cur ^ 1, kb + 32);
      if constexpr (NF == 4)
        asm volatile("s_waitcnt vmcnt(4)" ::: "memory");
      else
        asm volatile("s_waitcnt vmcnt(3)" ::: "memory");
    } else {
      asm volatile("s_waitcnt vmcnt(0)" ::: "memory");
    }
    __builtin_amdgcn_s_barrier();

    float sv[8], tv[8];
    if (BNA) {
      float4 s0 = *(const float4*)&sS[kb + lk];
      float4 s1 = *(const float4*)&sS[kb + lk + 4];
      float4 t0 = *(const float4*)&sT[kb + lk];
      float4 t1 = *(const float4*)&sT[kb + lk + 4];
      sv[0] = s0.x; sv[1] = s0.y; sv[2] = s0.z; sv[3] = s0.w;
      sv[4] = s1.x; sv[5] = s1.y; sv[6] = s1.z; sv[7] = s1.w;
      tv[0] = t0.x; tv[1] = t0.y; tv[2] = t0.z; tv[3] = t0.w;
      tv[4] = t1.x; tv[5] = t1.y; tv[6] = t1.z; tv[7] = t1.w;
    }
    bf16x8 bfr[NF];
#pragma unroll
    for (int n = 0; n < NF; ++n)
      bfr[n] = *(const bf16x8*)&Blds[cur][((((wc * NF + n) << 4) + lr) << 5) + lk];
#pragma unroll
    for (int m = 0; m < 8; ++m) {
      bf16x8 af = *(const bf16x8*)&Alds[cur][(((wr << 7) + (m << 4) + lr) << 5) + lk];
      if (BNA) {
        bf16x8 o;
#pragma unroll
        for (int j = 0; j < 8; ++j) {
          float v = fmaf(b2f((u16)af[j]), sv[j], tv[j]);
          v = v > 0.f ? v : v * 0.01f;
          o[j] = (short)f2b(v);
        }
        af = o;
      }
#pragma unroll
      for (int n = 0; n < NF; ++n)
        acc[m][n] = __builtin_amdgcn_mfma_f32_16x16x32_bf16(af, bfr[n], acc[m][n], 0, 0, 0);
    }
    __builtin_amdgcn_s_barrier();
    cur ^= 1;
  }

  float csm[NF], cq[NF];
#pragma unroll
  for (int n = 0; n < NF; ++n) { csm[n] = 0.f; cq[n] = 0.f; }
#pragma unroll
  for (int m = 0; m < 8; ++m) {
#pragma unroll
    for (int n = 0; n < NF; ++n) {
      const int col = wc * (NF * 16) + (n << 4) + lr;
#pragma unroll
      for (int j = 0; j < 4; ++j) {
        const size_t row = rowBase + (wr << 7) + (m << 4) + (lg << 2) + j;
        float v = acc[m][n][j];
        if (EPI == 0) {
          v = v > 0.f ? v : v * 0.01f;
          obf[row * ld_bf + col] = f2b(v);
        } else {
          obf[row * ld_bf + col] = f2b(v);
          csm[n] += v; cq[n] += v * v;
        }
      }
    }
  }
  if (EPI == 1) {
    const int shard = ((int)blockIdx.x & 7) * SHST;
#pragma unroll
    for (int n = 0; n < NF; ++n) {
      float s = csm[n], q = cq[n];
      s += __shfl_xor(s, 16); s += __shfl_xor(s, 32);
      q += __shfl_xor(q, 16); q += __shfl_xor(q, 32);
      if (lane < 16) {
        const int col = wc * (NF * 16) + (n << 4) + lane;
        atomicAdd(&stats[shard + col], s);
        atomicAdd(&stats[shard + M + col], q);
      }
    }
  }
}

// ---------------- EVO-fused GEMM ----------------
__global__ __launch_bounds__(512) void gemm256_evo(const u16* __restrict__ W,
                                                   u16* __restrict__ obf,
                                                   const u16* __restrict__ Qo, const u16* __restrict__ Qd,
                                                   const int* __restrict__ od, const float* __restrict__ distb,
                                                   const float* __restrict__ w512) {
  constexpr int KT = 8;
  __shared__ alignas(16) u16 Alds[2][256 * 32];
  __shared__ alignas(16) u16 Blds[2][256 * 32];
  __shared__ float sW[256], sDist[256];
  __shared__ int sO[256], sD[256];
  const int tid = threadIdx.x;
  const int lane = tid & 63;
  const int w = tid >> 6;
  const int wr = w >> 2, wc = w & 3;
  const size_t rowBase = (size_t)blockIdx.x * 256;
  const int crow = lane >> 2, ccol = (lane & 3) << 3;
  const int arow = tid >> 1;
  const int acol = (tid & 1) << 4;
  const int lr = lane & 15, lk = (lane >> 4) << 3, lg = lane >> 4;

  if (tid < 256) {
    int2 p = ((const int2*)od)[rowBase + tid];
    sO[tid] = p.x; sD[tid] = p.y;
    sDist[tid] = distb[rowBase + tid];
    sW[tid] = w512[tid];
  }
  __syncthreads();

  auto stageB = [&](int buf, int kb) {
#pragma unroll
    for (int i = 0; i < 2; ++i) {
      int c = w * 2 + i;
      const u16* src = W + (size_t)((c << 4) + crow) * 256 + kb + ccol;
      g2lds16(src, &Blds[buf][(c << 4) << 5]);
    }
  };
  auto loadA = [&](int kb, bf16x8& r0, bf16x8& r1, bf16x8& r2, bf16x8& r3) {
    const u16* qo = Qo + (size_t)sO[arow] * 256 + kb + acol;
    const u16* qd = Qd + (size_t)sD[arow] * 256 + kb + acol;
    r0 = *(const bf16x8*)qo; r1 = *(const bf16x8*)(qo + 8);
    r2 = *(const bf16x8*)qd; r3 = *(const bf16x8*)(qd + 8);
  };
  auto writeA = [&](int buf, int kb, bf16x8 r0, bf16x8 r1, bf16x8 r2, bf16x8 r3) {
    float dist = sDist[arow];
    bf16x8 w0, w1;
#pragma unroll
    for (int j = 0; j < 8; ++j) {
      float v = b2f((u16)r0[j]) + b2f((u16)r2[j]) + dist * sW[kb + acol + j];
      w0[j] = (short)f2b(lrelu(v, 0.01f));
      float v2 = b2f((u16)r1[j]) + b2f((u16)r3[j]) + dist * sW[kb + acol + 8 + j];
      w1[j] = (short)f2b(lrelu(v2, 0.01f));
    }
    *(bf16x8*)&Alds[buf][arow * 32 + acol] = w0;
    *(bf16x8*)&Alds[buf][arow * 32 + acol + 8] = w1;
  };

  f32x4 acc[8][4];
  const f32x4 z4 = {0.f, 0.f, 0.f, 0.f};
#pragma unroll
  for (int m = 0; m < 8; ++m)
#pragma unroll
    for (int n = 0; n < 4; ++n) acc[m][n] = z4;

  bf16x8 p0, p1, p2, p3;
  {
    bf16x8 c0, c1, c2, c3;
    loadA(0, c0, c1, c2, c3);
    writeA(0, 0, c0, c1, c2, c3);
  }
  stageB(0, 0);
  fence();
  loadA(32, p0, p1, p2, p3);
  fence();
  waitv<4>();
  waitl0();
  __builtin_amdgcn_s_barrier();

  int cur = 0;
  for (int kt = 0; kt < KT; ++kt) {
    const int kb = kt << 5;
    const bool hasN = kt + 1 < KT, hasNN = kt + 2 < KT;
    bf16x8 bfr[4];
#pragma unroll
    for (int n = 0; n < 4; ++n)
      bfr[n] = *(const bf16x8*)&Blds[cur][((((wc << 2) + n) << 4) + lr) * 32 + lk];
    if (hasN) stageB(cur ^ 1, kb + 32);
    fence();
    bf16x8 q0, q1, q2, q3;
    if (hasNN) loadA(kb + 64, q0, q1, q2, q3);
    fence();
#pragma unroll
    for (int m = 0; m < 8; ++m) {
      bf16x8 af = *(const bf16x8*)&Alds[cur][(((wr << 7) + (m << 4) + lr) << 5) + lk];
#pragma unroll
      for (int n = 0; n < 4; ++n)
        acc[m][n] = __builtin_amdgcn_mfma_f32_16x16x32_bf16(af, bfr[n], acc[m][n], 0, 0, 0);
    }
    if (hasN) {
      if (hasNN) waitv<6>(); else waitv<2>();
      writeA(cur ^ 1, kb + 32, p0, p1, p2, p3);
      p0 = q0; p1 = q1; p2 = q2; p3 = q3;
      if (hasNN) waitv<4>(); else waitv<0>();
      waitl0();
    }
    __builtin_amdgcn_s_barrier();
    cur ^= 1;
  }

#pragma unroll
  for (int m = 0; m < 8; ++m) {
#pragma unroll
    for (int n = 0; n < 4; ++n) {
      const int col = (wc << 6) + (n << 4) + lr;
#pragma unroll
      for (int j = 0; j < 4; ++j) {
        const size_t row = rowBase + (wr << 7) + (m << 4) + (lg << 2) + j;
        float v = acc[m][n][j];
        v = v > 0.f ? v : v * 0.01f;
        obf[row * 256 + col] = f2b(v);
      }
    }
  }
}

// ---------------- gemm320: [out_evo | pre1+stats] = [h4|S](Bx160) @ wTail(320x160)^T ----------------
__global__ __launch_bounds__(512) void gemm320(const u16* __restrict__ A, const u16* __restrict__ W,
                                               float* __restrict__ oevo, u16* __restrict__ opre,
                                               float* __restrict__ stats) {
  constexpr int KT = 5;
  __shared__ alignas(16) u16 Alds[2][256 * 32];
  __shared__ alignas(16) u16 Blds[2][320 * 32];
  const int tid = threadIdx.x;
  const int lane = tid & 63;
  const int w = tid >> 6;
  const int wr = w >> 2, wc = w & 3;
  const size_t rowBase = (size_t)blockIdx.x * 256;
  const int crow = lane >> 2, ccol = (lane & 3) << 3;
  const int lr = lane & 15, lk = (lane >> 4) << 3, lg = lane >> 4;

  f32x4 acc[8][5];
  const f32x4 z4 = {0.f, 0.f, 0.f, 0.f};
#pragma unroll
  for (int m = 0; m < 8; ++m)
#pragma unroll
    for (int n = 0; n < 5; ++n) acc[m][n] = z4;

  auto stage = [&](int buf, int kb) {
#pragma unroll
    for (int i = 0; i < 2; ++i) {
      int c = w * 2 + i;
      const u16* src = A + (rowBase + (c << 4) + crow) * 160 + kb + ccol;
      g2lds16(src, &Alds[buf][(c << 4) << 5]);
    }
    if (w < 4) {
#pragma unroll
      for (int i = 0; i < 3; ++i) {
        int c = w * 3 + i;
        const u16* src = W + (size_t)((c << 4) + crow) * 160 + kb + ccol;
        g2lds16(src, &Blds[buf][(c << 4) << 5]);
      }
    } else {
#pragma unroll
      for (int i = 0; i < 2; ++i) {
        int c = 12 + (w - 4) * 2 + i;
        const u16* src = W + (size_t)((c << 4) + crow) * 160 + kb + ccol;
        g2lds16(src, &Blds[buf][(c << 4) << 5]);
      }
    }
  };

  stage(0, 0);
  int cur = 0;
  for (int kt = 0; kt < KT; ++kt) {
    if (kt + 1 < KT) {
      stage(cur ^ 1, (kt + 1) << 5);
      // per-wave counted wait: equals the number of loads just issued
      if (w < 4) waitv<5>(); else waitv<4>();
    } else {
      waitv<0>();
    }
    __builtin_amdgcn_s_barrier();
    bf16x8 bfr[5];
#pragma unroll
    for (int n = 0; n < 5; ++n)
      bfr[n] = *(const bf16x8*)&Blds[cur][(((wc * 80 + (n << 4) + lr)) << 5) + lk];
#pragma unroll
    for (int m = 0; m < 8; ++m) {
      bf16x8 af = *(const bf16x8*)&Alds[cur][(((wr << 7) + (m << 4) + lr) << 5) + lk];
#pragma unroll
      for (int n = 0; n < 5; ++n)
        acc[m][n] = __builtin_amdgcn_mfma_f32_16x16x32_bf16(af, bfr[n], acc[m][n], 0, 0, 0);
    }
    __builtin_amdgcn_s_barrier();
    cur ^= 1;
  }

  float csm[5], cq[5];
#pragma unroll
  for (int n = 0; n < 5; ++n) { csm[n] = 0.f; cq[n] = 0.f; }
#pragma unroll
  for (int m = 0; m < 8; ++m) {
#pragma unroll
    for (int n = 0; n < 5; ++n) {
      const int col = wc * 80 + (n << 4) + lr;
#pragma unroll
      for (int j = 0; j < 4; ++j) {
        const size_t row = rowBase + (wr << 7) + (m << 4) + (lg << 2) + j;
        float v = acc[m][n][j];
        if (col < 64) {
          oevo[row * 64 + col] = v;
        } else {
          opre[row * 256 + (col - 64)] = f2b(v);
          csm[n] += v; cq[n] += v * v;
        }
      }
    }
  }
  const int shard = ((int)blockIdx.x & 7) * SHST;
#pragma unroll
  for (int n = 0; n < 5; ++n) {
    float s = csm[n], q = cq[n];
    s += __shfl_xor(s, 16); s += __shfl_xor(s, 32);
    q += __shfl_xor(q, 16); q += __shfl_xor(q, 32);
    if (lane < 16) {
      const int col = wc * 80 + (n << 4) + lane;
      if (col >= 64) {
        atomicAdd(&stats[shard + col - 64], s);
        atomicAdd(&stats[shard + 256 + col - 64], q);
      }
    }
  }
}

// ---------------- fused BN4 + final dot (sharded stats) ----------------
__global__ __launch_bounds__(256) void k_fout4(const u16* __restrict__ pre, const float* __restrict__ st,
                                               const float* __restrict__ g, const float* __restrict__ b,
                                               const float* __restrict__ W, float* __restrict__ out,
                                               float invB) {
  __shared__ float smu[128], srs[128], sg[128], sb[128], sw[128];
  if (threadIdx.x < 128) {
    int c = threadIdx.x;
    float s0 = 0.f, q0 = 0.f;
#pragma unroll
    for (int sh = 0; sh < 8; ++sh) {
      s0 += st[sh * SHST + c];
      q0 += st[sh * SHST + 128 + c];
    }
    float mu = s0 * invB;
    float var = q0 * invB - mu * mu;
    smu[c] = mu;
    srs[c] = rsqrtf(var + 1e-5f);
    sg[c] = g[c];
    sb[c] = b[c];
    sw[c] = W[c];
  }
  __syncthreads();
  int bi = blockIdx.x * 256 + threadIdx.x;
  const u16* hp = pre + (size_t)bi * 128;
  float acc = 0.f;
#pragma unroll
  for (int k = 0; k < 128; k += 8) {
    bf16x8 u = *(const bf16x8*)(hp + k);
#pragma unroll
    for (int j = 0; j < 8; ++j) {
      int c = k + j;
      float v = (b2f((u16)u[j]) - smu[c]) * srs[c] * sg[c] + sb[c];
      v = b2f(f2b(lrelu(v, 0.01f)));
      acc += v * sw[c];
    }
  }
  out[bi] = acc;
}

// ---------------- launch ----------------
extern "C" void kernel_launch(void* const* d_in, const int* in_sizes, int n_in,
                              void* d_out, int out_size, void* d_ws, size_t ws_size,
                              hipStream_t stream) {
  (void)in_sizes; (void)n_in; (void)out_size; (void)ws_size;

  const float* x0 = (const float*)d_in[0];
  const int* ei0 = (const int*)d_in[1];
  const float* ea0 = (const float*)d_in[2];
  const float* x1 = (const float*)d_in[3];
  const int* ei1 = (const int*)d_in[4];
  const float* ea1 = (const float*)d_in[5];
  const float* dm = (const float*)d_in[6];
  const float* nv = (const float*)d_in[7];
  const int* od = (const int*)d_in[8];
  const float* Wl0 = (const float*)d_in[9];
  const float* bl0 = (const float*)d_in[10];
  const float* Wr0 = (const float*)d_in[11];
  const float* br0 = (const float*)d_in[12];
  const float* We0 = (const float*)d_in[13];
  const float* att0 = (const float*)d_in[14];
  const float* bia0 = (const float*)d_in[15];
  const float* Wl1 = (const float*)d_in[16];
  const float* bl1 = (const float*)d_in[17];
  const float* Wr1 = (const float*)d_in[18];
  const float* br1 = (const float*)d_in[19];
  const float* We1 = (const float*)d_in[20];
  const float* att1 = (const float*)d_in[21];
  const float* bia1 = (const float*)d_in[22];
  const float* eW1 = (const float*)d_in[23];
  const float* eW2 = (const float*)d_in[24];
  const float* eW3 = (const float*)d_in[25];
  const float* eW4 = (const float*)d_in[26];
  const float* eWo = (const float*)d_in[27];
  const float* fW1 = (const float*)d_in[28];
  const float* fW2 = (const float*)d_in[29];
  const float* fW3 = (const float*)d_in[30];
  const float* fW4 = (const float*)d_in[31];
  const float* fWo = (const float*)d_in[32];
  const float* fg[4] = {(const float*)d_in[33], (const float*)d_in[35], (const float*)d_in[37], (const float*)d_in[39]};
  const float* fb[4] = {(const float*)d_in[34], (const float*)d_in[36], (const float*)d_in[38], (const float*)d_in[40]};

  float* out_inf = (float*)d_out;
  float* out_a1 = out_inf + NB;
  float* out_a2 = out_a1 + (size_t)ET * 4;
  float* out_evo = out_a2 + (size_t)ET * 4;

  // ---- workspace carve ----
  char* base = (char*)d_ws;
  size_t cur = 0;
  auto carve = [&](size_t bytes) -> char* {
    char* p = base + cur;
    cur += (bytes + 255) & ~(size_t)255;
    return p;
  };
  u16* bufA = (u16*)carve((size_t)NB * 256 * 2);
  u16* bufB = (u16*)carve((size_t)NB * 256 * 2);
  u16* bufC = (u16*)carve((size_t)NB * 160 * 2);
  float* n1 = (float*)carve((size_t)NN * 128 * 4);
  float* n2 = (float*)carve((size_t)NN * 128 * 4);
  u16* Qob = (u16*)carve((size_t)NN * 256 * 2);
  u16* Qdb = (u16*)carve((size_t)NN * 256 * 2);
  float* xl = (float*)carve((size_t)2 * NN * 128 * 4);
  float* xr = (float*)carve((size_t)2 * NN * 128 * 4);
  // stats (8 shards x SHST) immediately followed by cnt/wr: one merged memset
  float* stats = (float*)carve((size_t)8 * SHST * 4);
  int* cw = (int*)carve((size_t)4 * NN * 4);            // cnt[2*NN] then wr[2*NN]
  int* cnt = cw;
  int* wr = cw + 2 * NN;
  int* cs = (int*)carve((size_t)2 * (NN + 1) * 4);
  int2* csr = (int2*)carve((size_t)2 * ET * 8);
  float* m_out = (float*)carve((size_t)2 * NN * 4 * 4);
  float* den_out = (float*)carve((size_t)2 * NN * 4 * 4);
  float* asum = (float*)carve((size_t)2 * NN * 8 * 4);
  float* scr = (float*)carve((size_t)2 * ET * 4 * 4);
  float* distb = (float*)carve((size_t)NB * 4);
  float* w512 = (float*)carve(1024);
  float* W1T = (float*)carve(512 * 256 * 4);
  float* st[4] = {stats, stats + 512, stats + 1024, stats + 1536};
  u16* eW2b = (u16*)carve(256 * 256 * 2);
  u16* eW3b = (u16*)carve(256 * 256 * 2);
  u16* eW4b = (u16*)carve(128 * 256 * 2);
  u16* fW2b = (u16*)carve(256 * 256 * 2);
  u16* fW3b = (u16*)carve(256 * 256 * 2);
  u16* fW4b = (u16*)carve(128 * 256 * 2);
  u16* wTail = (u16*)carve(320 * 160 * 2);

  // ---- prep ----
  k_prep<<<1833, 256, 0, stream>>>(eW2, eW3, eW4, eWo, fW1, fW2, fW3, fW4, eW1,
                                   eW2b, eW3b, eW4b, fW2b, fW3b, fW4b,
                                   W1T, w512, wTail);
  hipMemsetAsync(stats, 0, (size_t)8 * SHST * 4 + (size_t)4 * NN * 4, stream);
  k_sprep<<<NB / 256, 256, 0, stream>>>(od, dm, nv, distb, bufC);

  // ---- GATv2 x2, batched ----
  k_count2<<<(2 * ET + 255) / 256, 256, 0, stream>>>(ei0, ei1, cnt);
  k_scan2<<<2, 1024, 0, stream>>>(cnt, cs);
  k_fill2<<<(2 * ET + 255) / 256, 256, 0, stream>>>(ei0, ei1, cs, wr, csr);
  k_asum2<<<2 * NN / 4, 256, 0, stream>>>(csr, cs, ea0, ea1, asum);
  k_xlr2<<<NN, 256, 0, stream>>>(x0, x1, Wl0, bl0, Wr0, br0, Wl1, bl1, Wr1, br1, xl, xr);
  k_scr2<<<4096, 256, 0, stream>>>(xl, xr, ei0, ei1, ea0, ea1, asum, We0, We1, att0, att1, scr);
  k_nodered2<<<2 * NN / 4, 256, 0, stream>>>(scr, csr, cs, xl, bia0, bia1, m_out, den_out, n1, n2);
  k_alpha2<<<(2 * ET * 4 + 255) / 256, 256, 0, stream>>>(scr, ei0, ei1, m_out, den_out, out_a1, out_a2);

  // ---- evo ----
  k_qtab<<<NN / 16, 256, 0, stream>>>(n1, n2, W1T, Qob, Qdb);

  const float invB = 1.0f / (float)NB;
  const int GB = NB / 256;
  gemm256_evo<<<GB, 512, 0, stream>>>(eW2b, bufA, Qob, Qdb, od, distb, w512);
  gemm256<4, 0, 0><<<GB, 512, 0, stream>>>(bufA, eW3b, 256, 256, bufB, 256, nullptr,
                                           nullptr, nullptr, nullptr, 0.f);
  gemm256<2, 0, 0><<<GB, 512, 0, stream>>>(bufB, eW4b, 256, 256, bufC, 160, nullptr,
                                           nullptr, nullptr, nullptr, 0.f);
  // merged: out_evo (f32) + pre1 (bf16 + sharded stats) from bufC
  gemm320<<<GB, 512, 0, stream>>>(bufC, wTail, out_evo, bufA, st[0]);

  // ---- flow (BN fused into consumer GEMMs; sharded stats) ----
  gemm256<4, 1, 1><<<GB, 512, 0, stream>>>(bufA, fW2b, 256, 256, bufB, 256, st[1],
                                           st[0], fg[0], fb[0], invB);
  gemm256<4, 1, 1><<<GB, 512, 0, stream>>>(bufB, fW3b, 256, 256, bufA, 256, st[2],
                                           st[1], fg[1], fb[1], invB);
  gemm256<2, 1, 1><<<GB, 512, 0, stream>>>(bufA, fW4b, 256, 256, bufB, 128, st[3],
                                           st[2], fg[2], fb[2], invB);
  k_fout4<<<NB / 256, 256, 0, stream>>>(bufB, st[3], fg[3], fb[3], fWo, out_inf, invB);
}